// Round 6
// baseline (907.257 us; speedup 1.0000x reference)
//
#include <hip/hip_runtime.h>

// GCN regressor: 2x (mean-aggregate + linear+ReLU) + per-graph mean + MLP head.
// N=50000 nodes, E=800000 edges, D_IN=128, H1=256, H2=128, G=256.
// R6: XCD-partitioned feature-chunked aggregation (chunk table resident in the
// owning XCD's 4MB L2; work-stealing queues keyed by XCC_ID, correct under any
// dispatch mapping). Readout fused into GEMM2 epilogue (sorted-gid run
// accumulation + sparse fp32 atomics). bf16 MFMA GEMMs as R5.

#define NUM_GRAPHS 256

typedef __attribute__((ext_vector_type(8))) short bf16x8;
typedef __attribute__((ext_vector_type(4))) float f32x4;

__device__ inline unsigned short f2bf(float f) {  // round-to-nearest-even
    unsigned u = __float_as_uint(f);
    return (unsigned short)((u + 0x7fff + ((u >> 16) & 1)) >> 16);
}
__device__ inline float bflo(unsigned u) { return __uint_as_float(u << 16); }
__device__ inline float bfhi(unsigned u) { return __uint_as_float(u & 0xffff0000u); }

// ---------------- CSR build ----------------

__global__ void count_kernel(const int* __restrict__ dst, int* __restrict__ cnt, int E) {
    int e = blockIdx.x * blockDim.x + threadIdx.x;
    if (e < E) atomicAdd(&cnt[dst[e]], 1);
}

__global__ void scan1_kernel(const int* __restrict__ cnt, int* __restrict__ offs,
                             int* __restrict__ part, int N) {
    __shared__ int wsum[16];
    int tid = threadIdx.x;
    int lane = tid & 63;
    int wid = tid >> 6;
    int i = blockIdx.x * 1024 + tid;
    int v = (i < N) ? cnt[i] : 0;
    int x = v;
    #pragma unroll
    for (int d = 1; d < 64; d <<= 1) {
        int y = __shfl_up(x, d, 64);
        if (lane >= d) x += y;
    }
    if (lane == 63) wsum[wid] = x;
    __syncthreads();
    if (wid == 0) {
        int s = (lane < 16) ? wsum[lane] : 0;
        #pragma unroll
        for (int d = 1; d < 16; d <<= 1) {
            int y = __shfl_up(s, d, 64);
            if (lane >= d) s += y;
        }
        if (lane < 16) wsum[lane] = s;
    }
    __syncthreads();
    int wbase = (wid > 0) ? wsum[wid - 1] : 0;
    if (i < N) offs[i] = wbase + x - v;
    if (tid == 1023) part[blockIdx.x] = wbase + x;
}

__global__ void scan2_kernel(int* __restrict__ part, int* __restrict__ offs, int N, int P) {
    int lane = threadIdx.x;  // 64 threads, P <= 64
    int v = (lane < P) ? part[lane] : 0;
    int x = v;
    #pragma unroll
    for (int d = 1; d < 64; d <<= 1) {
        int y = __shfl_up(x, d, 64);
        if (lane >= d) x += y;
    }
    if (lane < P) part[lane] = x - v;
    if (lane == 63) offs[N] = x;
}

__global__ void scan3_kernel(int* __restrict__ offs, const int* __restrict__ part, int N) {
    int i = blockIdx.x * 1024 + threadIdx.x;
    if (i < N) offs[i] += part[blockIdx.x];
}

__global__ void scatter_kernel(const int* __restrict__ src, const int* __restrict__ dst,
                               const int* __restrict__ offs, int* __restrict__ cur,
                               int* __restrict__ eidx, int E) {
    int e = blockIdx.x * blockDim.x + threadIdx.x;
    if (e < E) {
        int d = dst[e];
        int p = offs[d] + atomicAdd(&cur[d], 1);
        eidx[p] = src[e];
    }
}

// ---------------- graph segment starts (gids sorted) ----------------

__global__ void gstart_kernel(const int* __restrict__ gids, int* __restrict__ gstart, int N) {
    int n = blockIdx.x * blockDim.x + threadIdx.x;
    if (n >= N) return;
    int g = gids[n];
    int gp = (n == 0) ? -1 : gids[n - 1];
    for (int x = gp + 1; x <= g; ++x) gstart[x] = n;
    if (n == N - 1)
        for (int x = g + 1; x <= NUM_GRAPHS; ++x) gstart[x] = N;
}

// ---------------- fp32 -> bf16 cast ----------------

__global__ void cast_bf16_kernel(const float* __restrict__ in, unsigned short* __restrict__ out,
                                 int total4) {
    int i = blockIdx.x * blockDim.x + threadIdx.x;
    if (i < total4) {
        float4 v = *(const float4*)(in + (size_t)i * 4);
        ushort4 o;
        o.x = f2bf(v.x); o.y = f2bf(v.y); o.z = f2bf(v.z); o.w = f2bf(v.w);
        *(ushort4*)(out + (size_t)i * 4) = o;
    }
}

// ---------------- weight transpose+cast: Wt[n][k] = bf16(W[k][n]) ----------------

__global__ void transpose_cast_kernel(const float* __restrict__ W, unsigned short* __restrict__ Wt,
                                      int K) {
    __shared__ float tile[32][33];
    int k0 = blockIdx.x * 32;
    int n0 = blockIdx.y * 32;
    int tx = threadIdx.x & 31;
    int ty = threadIdx.x >> 5;
    #pragma unroll
    for (int i = 0; i < 4; ++i)
        tile[ty + i * 8][tx] = W[(size_t)(k0 + ty + i * 8) * 256 + n0 + tx];
    __syncthreads();
    #pragma unroll
    for (int i = 0; i < 4; ++i)
        Wt[(size_t)(n0 + ty + i * 8) * K + k0 + tx] = f2bf(tile[tx][ty + i * 8]);
}

// ---------------- XCD-partitioned chunked mean aggregation ----------------
// Chunk = 32 features (64 B/row = 1 cache line; 3.2 MB table fits 4 MB XCD L2).
// Workgroup prefers chunk == its physical XCD (mod NCHUNK); per-chunk atomic
// batch counters guarantee full coverage regardless of dispatch mapping.
// Wave: 4 edge-groups x 16 lanes x 2 feats; cross-group sum via shfl_xor.

template <int D>
__global__ void agg_chunked_kernel(const unsigned short* __restrict__ feat,
                                   const int* __restrict__ offs,
                                   const int* __restrict__ eidx,
                                   unsigned short* __restrict__ out,
                                   int* __restrict__ ctr, int N) {
    constexpr int NCHUNK = D / 32;
    __shared__ int sbase;
    unsigned xcc;
    asm volatile("s_getreg_b32 %0, hwreg(HW_REG_XCC_ID)" : "=s"(xcc));
    int pref = (int)(xcc & (NCHUNK - 1));
    int tid = threadIdx.x;
    int wave = tid >> 6, lane = tid & 63;
    int grp = lane >> 4, fl = lane & 15;

    for (int cc = 0; cc < NCHUNK; ++cc) {
        int chunk = (pref + cc) & (NCHUNK - 1);
        const unsigned short* featc = feat + chunk * 32 + fl * 2;
        for (;;) {
            if (tid == 0) sbase = atomicAdd(&ctr[chunk * 16], 16);
            __syncthreads();
            int base = sbase;
            __syncthreads();
            if (base >= N) break;
            #pragma unroll
            for (int t = 0; t < 4; ++t) {
                int n = base + wave * 4 + t;   // wave-uniform
                if (n >= N) continue;
                int beg = offs[n], end = offs[n + 1];
                float a0 = 0.0f, a1 = 0.0f;
                int j = beg + grp;
                for (; j + 4 < end; j += 8) {   // 2 independent loads in flight
                    int s0 = eidx[j], s1 = eidx[j + 4];
                    unsigned v0 = *(const unsigned*)(featc + (size_t)s0 * D);
                    unsigned v1 = *(const unsigned*)(featc + (size_t)s1 * D);
                    a0 += bflo(v0) + bflo(v1);
                    a1 += bfhi(v0) + bfhi(v1);
                }
                if (j < end) {
                    int s = eidx[j];
                    unsigned v = *(const unsigned*)(featc + (size_t)s * D);
                    a0 += bflo(v); a1 += bfhi(v);
                }
                a0 += __shfl_xor(a0, 16, 64); a0 += __shfl_xor(a0, 32, 64);
                a1 += __shfl_xor(a1, 16, 64); a1 += __shfl_xor(a1, 32, 64);
                if (grp == 0) {
                    int deg = end - beg;
                    float invd = 1.0f / (float)(deg > 0 ? deg : 1);
                    ushort2 o; o.x = f2bf(a0 * invd); o.y = f2bf(a1 * invd);
                    *(ushort2*)(out + (size_t)n * D + chunk * 32 + fl * 2) = o;
                }
            }
        }
    }
}

// ---------------- bf16 MFMA GEMM + bias + ReLU ----------------
// MODE 0: store bf16 to Cb.  MODE 1: fused per-graph-sum (sorted gids; local
// run accumulation per thread, atomic flush per run into gsum[g*256+col]).

template <int K, int MODE>
__launch_bounds__(256)
__global__ void gemm_mfma_kernel(const unsigned short* __restrict__ A,
                                 const unsigned short* __restrict__ Wt,
                                 const float* __restrict__ bias,
                                 unsigned short* __restrict__ Cb,
                                 const int* __restrict__ gids,
                                 float* __restrict__ gsum,
                                 int N) {
    constexpr int LDS = 40;
    __shared__ unsigned short As[64 * LDS];
    __shared__ unsigned short Bs[256 * LDS];

    int tid = threadIdx.x;
    int wave = tid >> 6;
    int lane = tid & 63;
    int m = lane & 15;
    int q = lane >> 4;
    int rowBase = blockIdx.x * 64;

    f32x4 acc[4][4] = {};

    for (int kc = 0; kc < K; kc += 32) {
        {
            int r = tid >> 2;
            int seg = tid & 3;
            int gr = rowBase + r;
            uint4 v = make_uint4(0, 0, 0, 0);
            if (gr < N) v = *(const uint4*)(A + (size_t)gr * K + kc + seg * 8);
            *(uint4*)&As[r * LDS + seg * 8] = v;
        }
        #pragma unroll
        for (int it = 0; it < 4; ++it) {
            int n = (tid >> 2) + it * 64;
            int seg = tid & 3;
            uint4 v = *(const uint4*)(Wt + (size_t)n * K + kc + seg * 8);
            *(uint4*)&Bs[n * LDS + seg * 8] = v;
        }
        __syncthreads();

        bf16x8 af[4], bfr[4];
        #pragma unroll
        for (int r = 0; r < 4; ++r)
            af[r] = *(const bf16x8*)&As[(r * 16 + m) * LDS + q * 8];
        #pragma unroll
        for (int c = 0; c < 4; ++c)
            bfr[c] = *(const bf16x8*)&Bs[(wave * 64 + c * 16 + m) * LDS + q * 8];
        #pragma unroll
        for (int r = 0; r < 4; ++r)
            #pragma unroll
            for (int c = 0; c < 4; ++c)
                acc[r][c] = __builtin_amdgcn_mfma_f32_16x16x32_bf16(af[r], bfr[c], acc[r][c], 0, 0, 0);
        __syncthreads();
    }

    if constexpr (MODE == 0) {
        #pragma unroll
        for (int c = 0; c < 4; ++c) {
            int col = wave * 64 + c * 16 + m;
            float bv = bias[col];
            #pragma unroll
            for (int r = 0; r < 4; ++r) {
                #pragma unroll
                for (int reg = 0; reg < 4; ++reg) {
                    int grow = rowBase + r * 16 + q * 4 + reg;
                    if (grow < N)
                        Cb[(size_t)grow * 256 + col] = f2bf(fmaxf(acc[r][c][reg] + bv, 0.0f));
                }
            }
        }
    } else {
        // stage this block's gids (rows visited in ascending order per thread)
        int* sgid = (int*)As;
        if (tid < 64) {
            int gr = rowBase + tid;
            sgid[tid] = (gr < N) ? gids[gr] : -1;
        }
        __syncthreads();
        #pragma unroll
        for (int c = 0; c < 4; ++c) {
            int col = wave * 64 + c * 16 + m;
            float bv = bias[col];
            float partsum = 0.0f;
            int gprev = -1;
            #pragma unroll
            for (int r = 0; r < 4; ++r) {
                #pragma unroll
                for (int reg = 0; reg < 4; ++reg) {
                    int lr = r * 16 + q * 4 + reg;
                    if (rowBase + lr < N) {
                        int g = sgid[lr];
                        float o = fmaxf(acc[r][c][reg] + bv, 0.0f);
                        if (g != gprev) {
                            if (gprev >= 0) atomicAdd(&gsum[gprev * 256 + col], partsum);
                            partsum = 0.0f;
                            gprev = g;
                        }
                        partsum += o;
                    }
                }
            }
            if (gprev >= 0) atomicAdd(&gsum[gprev * 256 + col], partsum);
        }
    }
}

// ---------------- MLP head ----------------

__global__ void final_kernel(const float* __restrict__ gsum, const int* __restrict__ gstart,
                             const float* __restrict__ Wr1, const float* __restrict__ br1,
                             const float* __restrict__ Wr2, const float* __restrict__ br2,
                             float* __restrict__ out) {
    int g = blockIdx.x;
    int j = threadIdx.x;  // 128
    int c = gstart[g + 1] - gstart[g];
    float invc = 1.0f / (float)(c > 0 ? c : 1);
    const float* gs = gsum + g * 256;
    float acc = br1[j];
    for (int k = 0; k < 256; ++k)
        acc += (gs[k] * invc) * Wr1[k * 128 + j];
    float p = acc * Wr2[j];
    #pragma unroll
    for (int d = 32; d > 0; d >>= 1) p += __shfl_down(p, d, 64);
    __shared__ float ws2[2];
    if ((j & 63) == 0) ws2[j >> 6] = p;
    __syncthreads();
    if (j == 0) out[g] = ws2[0] + ws2[1] + br2[0];
}

// ---------------- launch ----------------

extern "C" void kernel_launch(void* const* d_in, const int* in_sizes, int n_in,
                              void* d_out, int out_size, void* d_ws, size_t ws_size,
                              hipStream_t stream) {
    const float* h    = (const float*)d_in[0];
    const int*   src  = (const int*)d_in[1];
    const int*   dst  = (const int*)d_in[2];
    const int*   gids = (const int*)d_in[3];
    const float* W1   = (const float*)d_in[4];
    const float* b1   = (const float*)d_in[5];
    const float* W2   = (const float*)d_in[6];
    const float* b2   = (const float*)d_in[7];
    const float* Wr1  = (const float*)d_in[8];
    const float* br1  = (const float*)d_in[9];
    const float* Wr2  = (const float*)d_in[10];
    const float* br2  = (const float*)d_in[11];

    int N = in_sizes[0] / 128;
    int E = in_sizes[1];
    int nScanBlocks = (N + 1023) / 1024;  // 49 for N=50000, must be <= 64

    // workspace
    char* w = (char*)d_ws;
    unsigned short* hb     = (unsigned short*)w;  w += (size_t)N * 128 * sizeof(unsigned short);
    unsigned short* h1b    = (unsigned short*)w;  w += (size_t)N * 256 * sizeof(unsigned short);
    unsigned short* aggOut = (unsigned short*)w;  w += (size_t)N * 256 * sizeof(unsigned short);
    int* cnt    = (int*)w;              w += (size_t)N * sizeof(int);
    int* offs   = (int*)w;              w += (size_t)(N + 1) * sizeof(int);
    int* cur    = (int*)w;              w += (size_t)N * sizeof(int);
    int* eidx   = (int*)w;              w += (size_t)E * sizeof(int);
    int* part   = (int*)w;              w += 64 * sizeof(int);
    int* ctrA   = (int*)w;              w += 8 * 16 * sizeof(int);  // layer-1 chunk queues (64B padded)
    int* ctrB   = (int*)w;              w += 8 * 16 * sizeof(int);  // layer-2 chunk queues
    unsigned short* Wt1 = (unsigned short*)w;  w += 256 * 128 * sizeof(unsigned short);
    unsigned short* Wt2 = (unsigned short*)w;  w += 256 * 256 * sizeof(unsigned short);
    float* gsum = (float*)w;            w += (size_t)NUM_GRAPHS * 256 * sizeof(float);
    int* gstart = (int*)w;              w += (size_t)(NUM_GRAPHS + 1) * sizeof(int);

    hipMemsetAsync(cnt, 0, (size_t)N * sizeof(int), stream);
    hipMemsetAsync(cur, 0, (size_t)N * sizeof(int), stream);
    hipMemsetAsync(ctrA, 0, 2 * 8 * 16 * sizeof(int), stream);  // ctrA+ctrB contiguous
    hipMemsetAsync(gsum, 0, (size_t)NUM_GRAPHS * 256 * sizeof(float), stream);

    count_kernel<<<(E + 255) / 256, 256, 0, stream>>>(dst, cnt, E);
    scan1_kernel<<<nScanBlocks, 1024, 0, stream>>>(cnt, offs, part, N);
    scan2_kernel<<<1, 64, 0, stream>>>(part, offs, N, nScanBlocks);
    scan3_kernel<<<nScanBlocks, 1024, 0, stream>>>(offs, part, N);
    scatter_kernel<<<(E + 255) / 256, 256, 0, stream>>>(src, dst, offs, cur, eidx, E);
    gstart_kernel<<<(N + 255) / 256, 256, 0, stream>>>(gids, gstart, N);

    // weight prep
    transpose_cast_kernel<<<dim3(128 / 32, 256 / 32), 256, 0, stream>>>(W1, Wt1, 128);
    transpose_cast_kernel<<<dim3(256 / 32, 256 / 32), 256, 0, stream>>>(W2, Wt2, 256);

    // layer 1
    cast_bf16_kernel<<<(N * 128 / 4 + 255) / 256, 256, 0, stream>>>(h, hb, N * 128 / 4);
    agg_chunked_kernel<128><<<512, 256, 0, stream>>>(hb, offs, eidx, aggOut, ctrA, N);
    gemm_mfma_kernel<128, 0><<<(N + 63) / 64, 256, 0, stream>>>(aggOut, Wt1, b1, h1b, nullptr, nullptr, N);

    // layer 2 (readout fused into GEMM epilogue)
    agg_chunked_kernel<256><<<512, 256, 0, stream>>>(h1b, offs, eidx, aggOut, ctrB, N);
    gemm_mfma_kernel<256, 1><<<(N + 63) / 64, 256, 0, stream>>>(aggOut, Wt2, b2, nullptr, gids, gsum, N);

    final_kernel<<<NUM_GRAPHS, 128, 0, stream>>>(gsum, gstart, Wr1, br1, Wr2, br2, (float*)d_out);
}

// Round 7
// 358.964 us; speedup vs baseline: 2.5274x; 2.5274x over previous
//
#include <hip/hip_runtime.h>

// GCN regressor: 2x (mean-aggregate + linear+ReLU) + per-graph mean + MLP head.
// N=50000 nodes, E=800000 edges, D_IN=128, H1=256, H2=128, G=256.
// R7: R5 aggregation (one wave per node, bf16 gather — near structural floor;
// R6 chunked variant regressed 7x, do not revisit). Readout fused into GEMM2
// epilogue (sorted gids, run accumulation + sparse atomics). bf16 MFMA GEMMs.

#define NUM_GRAPHS 256

typedef __attribute__((ext_vector_type(8))) short bf16x8;
typedef __attribute__((ext_vector_type(4))) float f32x4;

__device__ inline unsigned short f2bf(float f) {  // round-to-nearest-even
    unsigned u = __float_as_uint(f);
    return (unsigned short)((u + 0x7fff + ((u >> 16) & 1)) >> 16);
}
__device__ inline float bflo(unsigned u) { return __uint_as_float(u << 16); }
__device__ inline float bfhi(unsigned u) { return __uint_as_float(u & 0xffff0000u); }

// ---------------- CSR build ----------------

__global__ void count_kernel(const int* __restrict__ dst, int* __restrict__ cnt, int E) {
    int e = blockIdx.x * blockDim.x + threadIdx.x;
    if (e < E) atomicAdd(&cnt[dst[e]], 1);
}

__global__ void scan1_kernel(const int* __restrict__ cnt, int* __restrict__ offs,
                             int* __restrict__ part, int N) {
    __shared__ int wsum[16];
    int tid = threadIdx.x;
    int lane = tid & 63;
    int wid = tid >> 6;
    int i = blockIdx.x * 1024 + tid;
    int v = (i < N) ? cnt[i] : 0;
    int x = v;
    #pragma unroll
    for (int d = 1; d < 64; d <<= 1) {
        int y = __shfl_up(x, d, 64);
        if (lane >= d) x += y;
    }
    if (lane == 63) wsum[wid] = x;
    __syncthreads();
    if (wid == 0) {
        int s = (lane < 16) ? wsum[lane] : 0;
        #pragma unroll
        for (int d = 1; d < 16; d <<= 1) {
            int y = __shfl_up(s, d, 64);
            if (lane >= d) s += y;
        }
        if (lane < 16) wsum[lane] = s;
    }
    __syncthreads();
    int wbase = (wid > 0) ? wsum[wid - 1] : 0;
    if (i < N) offs[i] = wbase + x - v;
    if (tid == 1023) part[blockIdx.x] = wbase + x;
}

__global__ void scan2_kernel(int* __restrict__ part, int* __restrict__ offs, int N, int P) {
    int lane = threadIdx.x;  // 64 threads, P <= 64
    int v = (lane < P) ? part[lane] : 0;
    int x = v;
    #pragma unroll
    for (int d = 1; d < 64; d <<= 1) {
        int y = __shfl_up(x, d, 64);
        if (lane >= d) x += y;
    }
    if (lane < P) part[lane] = x - v;
    if (lane == 63) offs[N] = x;
}

__global__ void scan3_kernel(int* __restrict__ offs, const int* __restrict__ part, int N) {
    int i = blockIdx.x * 1024 + threadIdx.x;
    if (i < N) offs[i] += part[blockIdx.x];
}

// scatter claims slots by decrementing cnt (dead after scan) — no `cur` array.
__global__ void scatter_kernel(const int* __restrict__ src, const int* __restrict__ dst,
                               const int* __restrict__ offs, int* __restrict__ cnt,
                               int* __restrict__ eidx, int E) {
    int e = blockIdx.x * blockDim.x + threadIdx.x;
    if (e < E) {
        int d = dst[e];
        int p = offs[d] + atomicSub(&cnt[d], 1) - 1;
        eidx[p] = src[e];
    }
}

// ---------------- graph segment starts (gids sorted) ----------------

__global__ void gstart_kernel(const int* __restrict__ gids, int* __restrict__ gstart, int N) {
    int n = blockIdx.x * blockDim.x + threadIdx.x;
    if (n >= N) return;
    int g = gids[n];
    int gp = (n == 0) ? -1 : gids[n - 1];
    for (int x = gp + 1; x <= g; ++x) gstart[x] = n;
    if (n == N - 1)
        for (int x = g + 1; x <= NUM_GRAPHS; ++x) gstart[x] = N;
}

// ---------------- fp32 -> bf16 cast ----------------

__global__ void cast_bf16_kernel(const float* __restrict__ in, unsigned short* __restrict__ out,
                                 int total4) {
    int i = blockIdx.x * blockDim.x + threadIdx.x;
    if (i < total4) {
        float4 v = *(const float4*)(in + (size_t)i * 4);
        ushort4 o;
        o.x = f2bf(v.x); o.y = f2bf(v.y); o.z = f2bf(v.z); o.w = f2bf(v.w);
        *(ushort4*)(out + (size_t)i * 4) = o;
    }
}

// ---------------- weight transpose+cast: Wt[n][k] = bf16(W[k][n]) ----------------

__global__ void transpose_cast_kernel(const float* __restrict__ W, unsigned short* __restrict__ Wt,
                                      int K) {
    __shared__ float tile[32][33];
    int k0 = blockIdx.x * 32;
    int n0 = blockIdx.y * 32;
    int tx = threadIdx.x & 31;
    int ty = threadIdx.x >> 5;
    #pragma unroll
    for (int i = 0; i < 4; ++i)
        tile[ty + i * 8][tx] = W[(size_t)(k0 + ty + i * 8) * 256 + n0 + tx];
    __syncthreads();
    #pragma unroll
    for (int i = 0; i < 4; ++i)
        Wt[(size_t)(n0 + ty + i * 8) * K + k0 + tx] = f2bf(tile[tx][ty + i * 8]);
}

// ---------------- mean aggregation: one wave per dst node, bf16 gather, fp32 accum ----------------

template <int D>
__global__ void agg_mean_bf16_kernel(const unsigned short* __restrict__ feat,
                                     const int* __restrict__ offs,
                                     const int* __restrict__ eidx,
                                     unsigned short* __restrict__ out, int N) {
    constexpr int VPL = D / 64;  // 2 or 4
    int wave = blockIdx.x * (blockDim.x >> 6) + (threadIdx.x >> 6);
    int lane = threadIdx.x & 63;
    if (wave >= N) return;
    int beg = offs[wave], end = offs[wave + 1];
    float acc[VPL];
    #pragma unroll
    for (int i = 0; i < VPL; ++i) acc[i] = 0.0f;

    int j = beg;
    for (; j + 8 <= end; j += 8) {
        int s[8];
        #pragma unroll
        for (int u = 0; u < 8; ++u) s[u] = eidx[j + u];
        if constexpr (VPL == 2) {
            unsigned v[8];
            #pragma unroll
            for (int u = 0; u < 8; ++u)
                v[u] = *(const unsigned*)(feat + (size_t)s[u] * D + lane * 2);
            #pragma unroll
            for (int u = 0; u < 8; ++u) { acc[0] += bflo(v[u]); acc[1] += bfhi(v[u]); }
        } else {
            uint2 v[8];
            #pragma unroll
            for (int u = 0; u < 8; ++u)
                v[u] = *(const uint2*)(feat + (size_t)s[u] * D + lane * 4);
            #pragma unroll
            for (int u = 0; u < 8; ++u) {
                acc[0] += bflo(v[u].x); acc[1] += bfhi(v[u].x);
                acc[2] += bflo(v[u].y); acc[3] += bfhi(v[u].y);
            }
        }
    }
    for (; j < end; ++j) {
        int s = eidx[j];
        if constexpr (VPL == 2) {
            unsigned v = *(const unsigned*)(feat + (size_t)s * D + lane * 2);
            acc[0] += bflo(v); acc[1] += bfhi(v);
        } else {
            uint2 v = *(const uint2*)(feat + (size_t)s * D + lane * 4);
            acc[0] += bflo(v.x); acc[1] += bfhi(v.x);
            acc[2] += bflo(v.y); acc[3] += bfhi(v.y);
        }
    }

    int deg = end - beg;
    float invd = 1.0f / (float)(deg > 0 ? deg : 1);
    unsigned short* orow = out + (size_t)wave * D + lane * VPL;
    if constexpr (VPL == 2) {
        ushort2 o; o.x = f2bf(acc[0] * invd); o.y = f2bf(acc[1] * invd);
        *(ushort2*)orow = o;
    } else {
        ushort4 o;
        o.x = f2bf(acc[0] * invd); o.y = f2bf(acc[1] * invd);
        o.z = f2bf(acc[2] * invd); o.w = f2bf(acc[3] * invd);
        *(ushort4*)orow = o;
    }
}

// ---------------- bf16 MFMA GEMM + bias + ReLU ----------------
// MODE 0: store bf16 to Cb.  MODE 1: fused per-graph-sum (sorted gids; local
// run accumulation per thread, atomic flush per run into gsum[g*256+col]).

template <int K, int MODE>
__launch_bounds__(256)
__global__ void gemm_mfma_kernel(const unsigned short* __restrict__ A,
                                 const unsigned short* __restrict__ Wt,
                                 const float* __restrict__ bias,
                                 unsigned short* __restrict__ Cb,
                                 const int* __restrict__ gids,
                                 float* __restrict__ gsum,
                                 int N) {
    constexpr int LDS = 40;
    __shared__ unsigned short As[64 * LDS];
    __shared__ unsigned short Bs[256 * LDS];

    int tid = threadIdx.x;
    int wave = tid >> 6;
    int lane = tid & 63;
    int m = lane & 15;
    int q = lane >> 4;
    int rowBase = blockIdx.x * 64;

    f32x4 acc[4][4] = {};

    for (int kc = 0; kc < K; kc += 32) {
        {
            int r = tid >> 2;
            int seg = tid & 3;
            int gr = rowBase + r;
            uint4 v = make_uint4(0, 0, 0, 0);
            if (gr < N) v = *(const uint4*)(A + (size_t)gr * K + kc + seg * 8);
            *(uint4*)&As[r * LDS + seg * 8] = v;
        }
        #pragma unroll
        for (int it = 0; it < 4; ++it) {
            int n = (tid >> 2) + it * 64;
            int seg = tid & 3;
            uint4 v = *(const uint4*)(Wt + (size_t)n * K + kc + seg * 8);
            *(uint4*)&Bs[n * LDS + seg * 8] = v;
        }
        __syncthreads();

        bf16x8 af[4], bfr[4];
        #pragma unroll
        for (int r = 0; r < 4; ++r)
            af[r] = *(const bf16x8*)&As[(r * 16 + m) * LDS + q * 8];
        #pragma unroll
        for (int c = 0; c < 4; ++c)
            bfr[c] = *(const bf16x8*)&Bs[(wave * 64 + c * 16 + m) * LDS + q * 8];
        #pragma unroll
        for (int r = 0; r < 4; ++r)
            #pragma unroll
            for (int c = 0; c < 4; ++c)
                acc[r][c] = __builtin_amdgcn_mfma_f32_16x16x32_bf16(af[r], bfr[c], acc[r][c], 0, 0, 0);
        __syncthreads();
    }

    if constexpr (MODE == 0) {
        #pragma unroll
        for (int c = 0; c < 4; ++c) {
            int col = wave * 64 + c * 16 + m;
            float bv = bias[col];
            #pragma unroll
            for (int r = 0; r < 4; ++r) {
                #pragma unroll
                for (int reg = 0; reg < 4; ++reg) {
                    int grow = rowBase + r * 16 + q * 4 + reg;
                    if (grow < N)
                        Cb[(size_t)grow * 256 + col] = f2bf(fmaxf(acc[r][c][reg] + bv, 0.0f));
                }
            }
        }
    } else {
        // stage this block's gids (rows visited in ascending order per thread)
        int* sgid = (int*)As;
        if (tid < 64) {
            int gr = rowBase + tid;
            sgid[tid] = (gr < N) ? gids[gr] : -1;
        }
        __syncthreads();
        #pragma unroll
        for (int c = 0; c < 4; ++c) {
            int col = wave * 64 + c * 16 + m;
            float bv = bias[col];
            float partsum = 0.0f;
            int gprev = -1;
            #pragma unroll
            for (int r = 0; r < 4; ++r) {
                #pragma unroll
                for (int reg = 0; reg < 4; ++reg) {
                    int lr = r * 16 + q * 4 + reg;
                    if (rowBase + lr < N) {
                        int g = sgid[lr];
                        float o = fmaxf(acc[r][c][reg] + bv, 0.0f);
                        if (g != gprev) {
                            if (gprev >= 0) atomicAdd(&gsum[gprev * 256 + col], partsum);
                            partsum = 0.0f;
                            gprev = g;
                        }
                        partsum += o;
                    }
                }
            }
            if (gprev >= 0) atomicAdd(&gsum[gprev * 256 + col], partsum);
        }
    }
}

// ---------------- MLP head ----------------

__global__ void final_kernel(const float* __restrict__ gsum, const int* __restrict__ gstart,
                             const float* __restrict__ Wr1, const float* __restrict__ br1,
                             const float* __restrict__ Wr2, const float* __restrict__ br2,
                             float* __restrict__ out) {
    int g = blockIdx.x;
    int j = threadIdx.x;  // 128
    int c = gstart[g + 1] - gstart[g];
    float invc = 1.0f / (float)(c > 0 ? c : 1);
    const float* gs = gsum + g * 256;
    float acc = br1[j];
    for (int k = 0; k < 256; ++k)
        acc += (gs[k] * invc) * Wr1[k * 128 + j];
    float p = acc * Wr2[j];
    #pragma unroll
    for (int d = 32; d > 0; d >>= 1) p += __shfl_down(p, d, 64);
    __shared__ float ws2[2];
    if ((j & 63) == 0) ws2[j >> 6] = p;
    __syncthreads();
    if (j == 0) out[g] = ws2[0] + ws2[1] + br2[0];
}

// ---------------- launch ----------------

extern "C" void kernel_launch(void* const* d_in, const int* in_sizes, int n_in,
                              void* d_out, int out_size, void* d_ws, size_t ws_size,
                              hipStream_t stream) {
    const float* h    = (const float*)d_in[0];
    const int*   src  = (const int*)d_in[1];
    const int*   dst  = (const int*)d_in[2];
    const int*   gids = (const int*)d_in[3];
    const float* W1   = (const float*)d_in[4];
    const float* b1   = (const float*)d_in[5];
    const float* W2   = (const float*)d_in[6];
    const float* b2   = (const float*)d_in[7];
    const float* Wr1  = (const float*)d_in[8];
    const float* br1  = (const float*)d_in[9];
    const float* Wr2  = (const float*)d_in[10];
    const float* br2  = (const float*)d_in[11];

    int N = in_sizes[0] / 128;
    int E = in_sizes[1];
    int nScanBlocks = (N + 1023) / 1024;  // 49 for N=50000, must be <= 64

    // workspace
    char* w = (char*)d_ws;
    unsigned short* hb     = (unsigned short*)w;  w += (size_t)N * 128 * sizeof(unsigned short);
    unsigned short* h1b    = (unsigned short*)w;  w += (size_t)N * 256 * sizeof(unsigned short);
    unsigned short* aggOut = (unsigned short*)w;  w += (size_t)N * 256 * sizeof(unsigned short);
    int* cnt    = (int*)w;              w += (size_t)N * sizeof(int);
    int* offs   = (int*)w;              w += (size_t)(N + 1) * sizeof(int);
    int* eidx   = (int*)w;              w += (size_t)E * sizeof(int);
    int* part   = (int*)w;              w += 64 * sizeof(int);
    unsigned short* Wt1 = (unsigned short*)w;  w += 256 * 128 * sizeof(unsigned short);
    unsigned short* Wt2 = (unsigned short*)w;  w += 256 * 256 * sizeof(unsigned short);
    float* gsum = (float*)w;            w += (size_t)NUM_GRAPHS * 256 * sizeof(float);
    int* gstart = (int*)w;              w += (size_t)(NUM_GRAPHS + 1) * sizeof(int);

    hipMemsetAsync(cnt, 0, (size_t)N * sizeof(int), stream);
    hipMemsetAsync(gsum, 0, (size_t)NUM_GRAPHS * 256 * sizeof(float), stream);

    count_kernel<<<(E + 255) / 256, 256, 0, stream>>>(dst, cnt, E);
    scan1_kernel<<<nScanBlocks, 1024, 0, stream>>>(cnt, offs, part, N);
    scan2_kernel<<<1, 64, 0, stream>>>(part, offs, N, nScanBlocks);
    scan3_kernel<<<nScanBlocks, 1024, 0, stream>>>(offs, part, N);
    scatter_kernel<<<(E + 255) / 256, 256, 0, stream>>>(src, dst, offs, cnt, eidx, E);
    gstart_kernel<<<(N + 255) / 256, 256, 0, stream>>>(gids, gstart, N);

    // weight prep
    transpose_cast_kernel<<<dim3(128 / 32, 256 / 32), 256, 0, stream>>>(W1, Wt1, 128);
    transpose_cast_kernel<<<dim3(256 / 32, 256 / 32), 256, 0, stream>>>(W2, Wt2, 256);

    // layer 1
    cast_bf16_kernel<<<(N * 128 / 4 + 255) / 256, 256, 0, stream>>>(h, hb, N * 128 / 4);
    agg_mean_bf16_kernel<128><<<(N + 3) / 4, 256, 0, stream>>>(hb, offs, eidx, aggOut, N);
    gemm_mfma_kernel<128, 0><<<(N + 63) / 64, 256, 0, stream>>>(aggOut, Wt1, b1, h1b, nullptr, nullptr, N);

    // layer 2 (readout fused into GEMM epilogue)
    agg_mean_bf16_kernel<256><<<(N + 3) / 4, 256, 0, stream>>>(h1b, offs, eidx, aggOut, N);
    gemm_mfma_kernel<256, 1><<<(N + 63) / 64, 256, 0, stream>>>(aggOut, Wt2, b2, nullptr, gids, gsum, N);

    final_kernel<<<NUM_GRAPHS, 128, 0, stream>>>(gsum, gstart, Wr1, br1, Wr2, br2, (float*)d_out);
}